// Round 8
// baseline (240.246 us; speedup 1.0000x reference)
//
#include <hip/hip_runtime.h>
#include <stdint.h>
#include <stddef.h>

// B=32, S=1024, E=768, HD=64, NIP=49.  out = softmax(mask(QK^T/8)) @ V.
// k0: Wt[192][768] bf16 row-major (coalesced W reads, scattered L2 writes)
//     + padneg[32][1024] f32 (pad ? -16384 : 0)
// k1: QKV proj "R4 done right": NO LDS, NO BARRIERS. M=32 rows/wave,
//     W fragments explicitly double-buffered in REGISTERS (wv[2][24],
//     one full stage prefetched ahead; each 1KB frag load feeds 2 MFMAs),
//     X double-buffered f32->bf16 via cvt_pk. Each frag load = 16 fully
//     used 64B lines of L2-hot Wt. 256 blocks = 1/CU, fully independent
//     waves. V written transposed Vt[b][d][s]; Q pre-scaled 1/8*log2(e).
// k2: flash attn, BM=64, BN=128, SWAPPED QK^T (mfma(K,Q)) so P lives
//     per-query in registers; P->bf16 A-frags via v_cvt_pk_bf16_f32 +
//     permlane32/16_swap butterfly (no LDS P strip); pad mask folded into
//     QK^T accumulator init via padneg; fixed-max softmax, row-sum via
//     ones-tile MFMA, K/V via global_load_lds 1-tile-ahead prefetch, LPT.

typedef __attribute__((ext_vector_type(8))) short bf16x8;
typedef __attribute__((ext_vector_type(4))) float f32x4;

#define NIP 49
#define QSCALE 0.18033688011112042f /* 0.125 * log2(e) */

#define GLDS16(g, l)                                      \
  __builtin_amdgcn_global_load_lds(                       \
      (const __attribute__((address_space(1))) void*)(g), \
      (__attribute__((address_space(3))) void*)(l), 16, 0, 0)

__device__ __forceinline__ short f2b(float f) {
  union { float f; uint32_t u; } c; c.f = f;
  uint32_t u = c.u;
  uint32_t r = (u + 0x7fffu + ((u >> 16) & 1u)) >> 16;  // RNE
  return (short)(uint16_t)r;
}

// pack two f32 -> two bf16 (RNE) in one VALU op; lo -> bits[15:0]
__device__ __forceinline__ uint32_t pk2(float lo, float hi) {
  uint32_t r;
  asm("v_cvt_pk_bf16_f32 %0, %1, %2" : "=v"(r) : "v"(lo), "v"(hi));
  return r;
}

// ---------------- kernel 0: W -> Wt bf16 [192][768]; padneg ----------------
// One thread per SOURCE element (coalesced reads); scattered 2B writes land
// in L2 (Wt is 288 KB, L2-resident) and merge before writeback.
__global__ __launch_bounds__(256) void wt_kernel(
    const float* __restrict__ Wq, const float* __restrict__ Wk,
    const float* __restrict__ Wv, const int* __restrict__ pad,
    short* __restrict__ Wt, float* __restrict__ padneg) {
  int e = blockIdx.x * 256 + threadIdx.x;  // 0..147455
  int m = e / 49152;
  int idx2 = e - m * 49152;  // k*64 + n_loc
  int k = idx2 >> 6, n = idx2 & 63;
  const float* W = (m == 0) ? Wq : (m == 1) ? Wk : Wv;
  Wt[(size_t)(m * 64 + n) * 768 + k] = f2b(W[idx2]);
  if (e < 32768) padneg[e] = pad[e] ? -16384.f : 0.f;
}

// ---------------- kernel 1: QKV projection (reg-staged W, no sync) --------
// 256 blocks x 256 threads; wave = independent 32-row strip (block 128 rows).
__global__ __launch_bounds__(256, 1) void proj_kernel(
    const float* __restrict__ X, const float* __restrict__ bq,
    const float* __restrict__ bk, const float* __restrict__ bv,
    const short* __restrict__ Wt, short* __restrict__ Qg,
    short* __restrict__ Kg, short* __restrict__ Vt) {
  const int tid = threadIdx.x;
  const int wid = tid >> 6, lane = tid & 63;
  const int l15 = lane & 15, q4 = lane >> 4;
  const int r0 = blockIdx.x * 128;   // block rows (within one batch: 1024%128==0)
  const int wr0 = r0 + wid * 32;     // wave rows

  // X: two 16-row tiles per wave; lane covers row rt*16+l15, k-slice q4*8..+7
  // per ks-half. 8 float4/lane/stage, double-buffered.
  const float* xr0 = X + (size_t)(wr0 + l15) * 768;
  const float* xr1 = xr0 + 16 * 768;
  float4 xa[2][8];  // [slot][rt*4 + ks*2 + h]  (all indices static)
  auto xload = [&](int slot, int st) {
    const int kb = st * 64 + q4 * 8;
#pragma unroll
    for (int ks = 0; ks < 2; ++ks)
#pragma unroll
      for (int h = 0; h < 2; ++h) {
        xa[slot][0 * 4 + ks * 2 + h] = *(const float4*)(xr0 + kb + ks * 32 + h * 4);
        xa[slot][1 * 4 + ks * 2 + h] = *(const float4*)(xr1 + kb + ks * 32 + h * 4);
      }
  };
  auto mkfrag = [&](int slot, int rt, int ks) {
    union { uint32_t u[4]; bf16x8 v; } r;
    const float4 a = xa[slot][rt * 4 + ks * 2 + 0];
    const float4 b = xa[slot][rt * 4 + ks * 2 + 1];
    r.u[0] = pk2(a.x, a.y); r.u[1] = pk2(a.z, a.w);
    r.u[2] = pk2(b.x, b.y); r.u[3] = pk2(b.z, b.w);
    return r.v;
  };

  // W B-frags: lane (l15,q4) of frag (ks,c) reads 16B at
  // Wt[(c*16+l15)*768 + st*64 + ks*32 + q4*8] -> 16 fully-used 64B lines.
  // Double-buffered register file: 24 frags x 4 VGPR x 2 slots = 192 VGPR.
  const short* wbase = Wt + (size_t)l15 * 768 + q4 * 8;
  bf16x8 wv[2][24];  // [slot][ks*12 + c]
  auto wload = [&](int slot, int st) {
#pragma unroll
    for (int ks = 0; ks < 2; ++ks)
#pragma unroll
      for (int c = 0; c < 12; ++c)
        wv[slot][ks * 12 + c] =
            *(const bf16x8*)(wbase + (size_t)c * 12288 + st * 64 + ks * 32);
  };

  f32x4 acc[2][12];  // 96 VGPR
#pragma unroll
  for (int rt = 0; rt < 2; ++rt)
#pragma unroll
    for (int c = 0; c < 12; ++c) acc[rt][c] = (f32x4){0.f, 0.f, 0.f, 0.f};

  wload(0, 0);
  xload(0, 0);

#pragma unroll
  for (int st = 0; st < 12; ++st) {
    const int cur = st & 1;
    if (st + 1 < 12) {            // prefetch next stage into the other slot
      wload(cur ^ 1, st + 1);
      xload(cur ^ 1, st + 1);
    }
#pragma unroll
    for (int ks = 0; ks < 2; ++ks) {
      const bf16x8 a0 = mkfrag(cur, 0, ks);
      const bf16x8 a1 = mkfrag(cur, 1, ks);
#pragma unroll
      for (int c = 0; c < 12; ++c) {
        const bf16x8 bw = wv[cur][ks * 12 + c];
        acc[0][c] = __builtin_amdgcn_mfma_f32_16x16x32_bf16(a0, bw, acc[0][c], 0, 0, 0);
        acc[1][c] = __builtin_amdgcn_mfma_f32_16x16x32_bf16(a1, bw, acc[1][c], 0, 0, 0);
      }
    }
  }

  // epilogue: C/D col=l15, row=q4*4+rr (per rowtile rt)
  const int b = r0 >> 10, s0 = r0 & 1023;
#pragma unroll
  for (int c = 0; c < 12; ++c) {
    const int mtx = c >> 2;
    const int h = (c & 3) * 16 + l15;
    if (mtx < 2) {
      const float bias = (mtx == 0 ? bq : bk)[h];
      short* op = (mtx == 0) ? Qg : Kg;
#pragma unroll
      for (int rt = 0; rt < 2; ++rt)
#pragma unroll
        for (int rr = 0; rr < 4; ++rr) {
          int row = wr0 + rt * 16 + q4 * 4 + rr;
          float v = acc[rt][c][rr] + bias;
          if (mtx == 0) v *= QSCALE;
          op[(size_t)row * 64 + h] = f2b(v);
        }
    } else {
      const float bias = bv[h];
#pragma unroll
      for (int rt = 0; rt < 2; ++rt) {
        uint2 sv;
        sv.x = pk2(acc[rt][c][0] + bias, acc[rt][c][1] + bias);
        sv.y = pk2(acc[rt][c][2] + bias, acc[rt][c][3] + bias);
        *(uint2*)(Vt + ((size_t)(b * 64 + h) << 10) +
                  (s0 + wid * 32 + rt * 16 + q4 * 4)) = sv;
      }
    }
  }
}

// ---------------- kernel 2: flash attention, BN=128, swapped QK^T ----------
// grid (32 batches fast, 16 levels); level 0 -> t=0, level L -> t=16-L (LPT).
__global__ __launch_bounds__(256, 2) void attn_kernel(
    const short* __restrict__ Qg, const short* __restrict__ Kg,
    const short* __restrict__ Vt, const float* __restrict__ padneg,
    float* __restrict__ out) {
  __shared__ short lK[2][2][128][32];  // [buf][dhalf][key][d32]  32 KB
  __shared__ short lV[2][4][64][32];   // [buf][kq][d][key32]     32 KB
  __shared__ short lOnes[16][32];      // ones B-tile (row0=1.0)  1 KB

  const int b = blockIdx.x;
  const int level = blockIdx.y;
  const int t = (level == 0) ? 0 : 16 - level;
  const int tid = threadIdx.x;
  const int wid = tid >> 6, lane = tid & 63;
  const int l15 = lane & 15, q4 = lane >> 4;
  const int qs = t * 64;
  const size_t base = (size_t)b * 1024;
  const int nkt = (t == 0) ? 8 : (t / 2 + 1);

  {  // init ones tile: 512 shorts
    int i0 = tid, i1 = tid + 256;
    ((short*)lOnes)[i0] = ((i0 >> 5) == 0) ? (short)0x3F80 : (short)0;
    if (i1 < 512) ((short*)lOnes)[i1] = ((i1 >> 5) == 0) ? (short)0x3F80 : (short)0;
  }

  // Q B-frags straight from global (lane row = query = qs + wid*16 + l15)
  const short* qrow = Qg + (base + qs + wid * 16 + l15) * 64;
  bf16x8 bq0 = *(const bf16x8*)(qrow + q4 * 8);
  bf16x8 bq1 = *(const bf16x8*)(qrow + 32 + q4 * 8);
  const int qi = qs + wid * 16 + l15;  // this lane's query row

  const int sr = lane >> 2, sc = (lane & 3) * 8;
  auto wlds_tile = [&](int buf, int kt) {
    const int kb = kt * 128;
    // K: 128 keys x 64 d; wave wid covers key quarter wid*32
#pragma unroll
    for (int i = 0; i < 4; ++i) {
      const int dh = i & 1, krow = wid * 32 + (i >> 1) * 16;
      GLDS16(Kg + (base + kb + krow + sr) * 64 + dh * 32 + sc,
             &lK[buf][dh][krow][0]);
    }
    // V: 64 d x 128 keys from Vt[b][d][s]; wave wid covers d strip wid*16
#pragma unroll
    for (int kq = 0; kq < 4; ++kq) {
      GLDS16(Vt + ((size_t)(b * 64 + wid * 16 + sr) << 10) + kb + kq * 32 + sc,
             &lV[buf][kq][wid * 16][0]);
    }
  };

  // padneg for this lane's keys: key = kb + c*16 + q4*4 + rr  -> float4
  float4 pnv[8];
  auto pnload = [&](int kt) {
#pragma unroll
    for (int c = 0; c < 8; ++c)
      pnv[c] = *(const float4*)(padneg + base + kt * 128 + c * 16 + q4 * 4);
  };

  pnload(0);
  wlds_tile(0, 0);
  __syncthreads();

  f32x4 o[5];  // o[4] = row-sum l via ones tile
#pragma unroll
  for (int c = 0; c < 5; ++c) o[c] = (f32x4){0.f, 0.f, 0.f, 0.f};

  for (int kt = 0; kt < nkt; ++kt) {
    const int cur = kt & 1;
    const int kb = kt * 128;

    // S^T = K Q^T: accumulator pre-loaded with padneg (pad mask is free)
    f32x4 s4[8];
#pragma unroll
    for (int c = 0; c < 8; ++c)
      s4[c] = (f32x4){pnv[c].x, pnv[c].y, pnv[c].z, pnv[c].w};

    if (kt + 1 < nkt) {
      wlds_tile(cur ^ 1, kt + 1);  // in flight until body-end barrier
      pnload(kt + 1);              // pnv already consumed into s4
    }

    // swapped QK^T: D row (q4*4+rr) = key, col (l15) = query
#pragma unroll
    for (int c = 0; c < 8; ++c) {
      bf16x8 a0 = *(const bf16x8*)&lK[cur][0][c * 16 + l15][q4 * 8];
      s4[c] = __builtin_amdgcn_mfma_f32_16x16x32_bf16(a0, bq0, s4[c], 0, 0, 0);
      bf16x8 a1 = *(const bf16x8*)&lK[cur][1][c * 16 + l15][q4 * 8];
      s4[c] = __builtin_amdgcn_mfma_f32_16x16x32_bf16(a1, bq1, s4[c], 0, 0, 0);
    }

    // fixed-max softmax in place: p = exp2(min(s,80)); causal/img masks
    const bool diag = (t == 0) ? (kt == 0) : (kt == nkt - 1);
    const bool img = (t == 0 && kt > 0);
#pragma unroll
    for (int c = 0; c < 8; ++c) {
#pragma unroll
      for (int rr = 0; rr < 4; ++rr) {
        float pv = exp2f(fminf(s4[c][rr], 80.f));
        if (diag) {
          int j = kb + c * 16 + q4 * 4 + rr;
          if (qi >= NIP && j > qi) pv = 0.f;
        }
        if (img) {
          if (qi >= NIP) pv = 0.f;
        }
        s4[c][rr] = pv;
      }
    }

    // PV: per 32-key block, assemble bf16 A-frag fully in registers.
    // w0..w3 = cvt_pk key-pairs; (X0,X2)=permlane16(permlane32(w0,w2)),
    // (X1,X3)= same on (w1,w3).  A-frag keys = q4*8 + 0..7.
#pragma unroll
    for (int m = 0; m < 4; ++m) {
      uint32_t w0 = pk2(s4[2 * m][0], s4[2 * m][1]);
      uint32_t w1 = pk2(s4[2 * m][2], s4[2 * m][3]);
      uint32_t w2 = pk2(s4[2 * m + 1][0], s4[2 * m + 1][1]);
      uint32_t w3 = pk2(s4[2 * m + 1][2], s4[2 * m + 1][3]);
      asm("v_permlane32_swap_b32 %0, %1" : "+v"(w0), "+v"(w2));
      asm("v_permlane32_swap_b32 %0, %1" : "+v"(w1), "+v"(w3));
      asm("v_permlane16_swap_b32 %0, %1" : "+v"(w0), "+v"(w2));
      asm("v_permlane16_swap_b32 %0, %1" : "+v"(w1), "+v"(w3));
      union { uint32_t u[4]; bf16x8 v; } af;
      af.u[0] = w0; af.u[1] = w1; af.u[2] = w2; af.u[3] = w3;
#pragma unroll
      for (int c = 0; c < 5; ++c) {
        bf16x8 bv = (c < 4) ? *(const bf16x8*)&lV[cur][m][c * 16 + l15][q4 * 8]
                            : *(const bf16x8*)&lOnes[l15][q4 * 8];
        o[c] = __builtin_amdgcn_mfma_f32_16x16x32_bf16(af.v, bv, o[c], 0, 0, 0);
      }
    }
    __syncthreads();
  }

#pragma unroll
  for (int rr = 0; rr < 4; ++rr) {
    float l = __shfl(o[4][rr], lane & 48, 64);  // col 0 of this quad
    const float inv = (l > 0.f) ? 1.0f / l : 0.f;
    const size_t row = base + qs + wid * 16 + q4 * 4 + rr;
#pragma unroll
    for (int c = 0; c < 4; ++c)
      out[row * 64 + c * 16 + l15] = o[c][rr] * inv;
  }
}

extern "C" void kernel_launch(void* const* d_in, const int* in_sizes, int n_in,
                              void* d_out, int out_size, void* d_ws, size_t ws_size,
                              hipStream_t stream) {
  const float* X  = (const float*)d_in[0];
  const float* Wq = (const float*)d_in[1];
  const float* bq = (const float*)d_in[2];
  const float* Wk = (const float*)d_in[3];
  const float* bk = (const float*)d_in[4];
  const float* Wv = (const float*)d_in[5];
  const float* bv = (const float*)d_in[6];
  const int* pad  = (const int*)d_in[8];
  float* out = (float*)d_out;

  short* Qg = (short*)d_ws;              // 4 MB
  short* Kg = Qg + 32768 * 64;           // 4 MB
  short* Vt = Kg + 32768 * 64;           // 4 MB, [32][64][1024]
  short* Wt = Vt + 32768 * 64;           // 288 KB, row-major [192][768]
  float* padneg = (float*)(Wt + 147456); // 128 KB

  wt_kernel<<<576, 256, 0, stream>>>(Wq, Wk, Wv, pad, Wt, padneg);
  proj_kernel<<<256, 256, 0, stream>>>(X, bq, bk, bv, Wt, Qg, Kg, Vt);
  attn_kernel<<<dim3(32, 16), 256, 0, stream>>>(Qg, Kg, Vt, padneg, out);
}

// Round 9
// 209.566 us; speedup vs baseline: 1.1464x; 1.1464x over previous
//
#include <hip/hip_runtime.h>
#include <stdint.h>
#include <stddef.h>

// B=32, S=1024, E=768, HD=64, NIP=49.  out = softmax(mask(QK^T/8)) @ V.
// k0: Wt[192][768] bf16 row-major (coalesced W reads, scattered L2 writes)
//     + padneg[32][1024] f32 (pad ? -16384 : 0)
// k1: QKV proj, NO LDS / NO BARRIERS, M=32 rows/wave, W+X double-buffered
//     in REGISTERS with the load->MFMA schedule PINNED by sched_barrier(0)
//     per stage (R8's VGPR=128 proved the compiler sank the prefetch loads
//     back to their uses, reproducing R4; the fence forces the pipeline
//     to exist: expect VGPR ~380). Each W frag load = 16 fully-used 64B
//     lines of L2-hot Wt, feeds 2 MFMAs. 256 blocks = 1/CU.
//     V written transposed Vt[b][d][s]; Q pre-scaled 1/8*log2(e).
// k2: flash attn, BM=64, BN=128, SWAPPED QK^T (mfma(K,Q)) so P lives
//     per-query in registers; P->bf16 A-frags via v_cvt_pk_bf16_f32 +
//     permlane32/16_swap butterfly (no LDS P strip); pad mask folded into
//     QK^T accumulator init via padneg; fixed-max softmax, row-sum via
//     ones-tile MFMA, K/V via global_load_lds 1-tile-ahead prefetch, LPT.

typedef __attribute__((ext_vector_type(8))) short bf16x8;
typedef __attribute__((ext_vector_type(4))) float f32x4;

#define NIP 49
#define QSCALE 0.18033688011112042f /* 0.125 * log2(e) */

#define GLDS16(g, l)                                      \
  __builtin_amdgcn_global_load_lds(                       \
      (const __attribute__((address_space(1))) void*)(g), \
      (__attribute__((address_space(3))) void*)(l), 16, 0, 0)

__device__ __forceinline__ short f2b(float f) {
  union { float f; uint32_t u; } c; c.f = f;
  uint32_t u = c.u;
  uint32_t r = (u + 0x7fffu + ((u >> 16) & 1u)) >> 16;  // RNE
  return (short)(uint16_t)r;
}

// pack two f32 -> two bf16 (RNE) in one VALU op; lo -> bits[15:0]
__device__ __forceinline__ uint32_t pk2(float lo, float hi) {
  uint32_t r;
  asm("v_cvt_pk_bf16_f32 %0, %1, %2" : "=v"(r) : "v"(lo), "v"(hi));
  return r;
}

// ---------------- kernel 0: W -> Wt bf16 [192][768]; padneg ----------------
// One thread per SOURCE element (coalesced reads); scattered 2B writes land
// in L2 (Wt is 288 KB, L2-resident) and merge before writeback.
__global__ __launch_bounds__(256) void wt_kernel(
    const float* __restrict__ Wq, const float* __restrict__ Wk,
    const float* __restrict__ Wv, const int* __restrict__ pad,
    short* __restrict__ Wt, float* __restrict__ padneg) {
  int e = blockIdx.x * 256 + threadIdx.x;  // 0..147455
  int m = e / 49152;
  int idx2 = e - m * 49152;  // k*64 + n_loc
  int k = idx2 >> 6, n = idx2 & 63;
  const float* W = (m == 0) ? Wq : (m == 1) ? Wk : Wv;
  Wt[(size_t)(m * 64 + n) * 768 + k] = f2b(W[idx2]);
  if (e < 32768) padneg[e] = pad[e] ? -16384.f : 0.f;
}

// ---------------- kernel 1: QKV projection (reg-staged W, pinned) ---------
// 256 blocks x 256 threads; wave = independent 32-row strip (block 128 rows).
__global__ __launch_bounds__(256, 1) void proj_kernel(
    const float* __restrict__ X, const float* __restrict__ bq,
    const float* __restrict__ bk, const float* __restrict__ bv,
    const short* __restrict__ Wt, short* __restrict__ Qg,
    short* __restrict__ Kg, short* __restrict__ Vt) {
  const int tid = threadIdx.x;
  const int wid = tid >> 6, lane = tid & 63;
  const int l15 = lane & 15, q4 = lane >> 4;
  const int r0 = blockIdx.x * 128;   // block rows (within one batch: 1024%128==0)
  const int wr0 = r0 + wid * 32;     // wave rows

  // X: two 16-row tiles per wave; lane covers row rt*16+l15, k-slice q4*8..+7
  // per ks-half. 8 float4/lane/stage, double-buffered.
  const float* xr0 = X + (size_t)(wr0 + l15) * 768;
  const float* xr1 = xr0 + 16 * 768;
  float4 xa[2][8];  // [slot][rt*4 + ks*2 + h]  (all indices static post-unroll)
  auto xload = [&](int slot, int st) {
    const int kb = st * 64 + q4 * 8;
#pragma unroll
    for (int ks = 0; ks < 2; ++ks)
#pragma unroll
      for (int h = 0; h < 2; ++h) {
        xa[slot][0 * 4 + ks * 2 + h] = *(const float4*)(xr0 + kb + ks * 32 + h * 4);
        xa[slot][1 * 4 + ks * 2 + h] = *(const float4*)(xr1 + kb + ks * 32 + h * 4);
      }
  };
  auto mkfrag = [&](int slot, int rt, int ks) {
    union { uint32_t u[4]; bf16x8 v; } r;
    const float4 a = xa[slot][rt * 4 + ks * 2 + 0];
    const float4 b = xa[slot][rt * 4 + ks * 2 + 1];
    r.u[0] = pk2(a.x, a.y); r.u[1] = pk2(a.z, a.w);
    r.u[2] = pk2(b.x, b.y); r.u[3] = pk2(b.z, b.w);
    return r.v;
  };

  // W B-frags: lane (l15,q4) of frag (ks,c) reads 16B at
  // Wt[(c*16+l15)*768 + st*64 + ks*32 + q4*8] -> 16 fully-used 64B lines.
  // Double-buffered register file: 24 frags x 4 VGPR x 2 slots = 192 VGPR.
  const short* wbase = Wt + (size_t)l15 * 768 + q4 * 8;
  bf16x8 wv[2][24];  // [slot][ks*12 + c]
  auto wload = [&](int slot, int st) {
#pragma unroll
    for (int ks = 0; ks < 2; ++ks)
#pragma unroll
      for (int c = 0; c < 12; ++c)
        wv[slot][ks * 12 + c] =
            *(const bf16x8*)(wbase + (size_t)c * 12288 + st * 64 + ks * 32);
  };

  f32x4 acc[2][12];  // 96 VGPR
#pragma unroll
  for (int rt = 0; rt < 2; ++rt)
#pragma unroll
    for (int c = 0; c < 12; ++c) acc[rt][c] = (f32x4){0.f, 0.f, 0.f, 0.f};

  wload(0, 0);
  xload(0, 0);

#pragma unroll
  for (int st = 0; st < 12; ++st) {
    const int cur = st & 1;
    if (st + 1 < 12) {            // prefetch next stage into the other slot
      wload(cur ^ 1, st + 1);
      xload(cur ^ 1, st + 1);
    }
    // PIN: all prefetch loads issue BEFORE this stage's MFMA cluster, and
    // the compiler cannot sink them back to their uses (R8 post-mortem:
    // without this fence it rematerializes the loads, VGPR=128, R4 perf).
    __builtin_amdgcn_sched_barrier(0);
#pragma unroll
    for (int ks = 0; ks < 2; ++ks) {
      const bf16x8 a0 = mkfrag(cur, 0, ks);
      const bf16x8 a1 = mkfrag(cur, 1, ks);
#pragma unroll
      for (int c = 0; c < 12; ++c) {
        const bf16x8 bw = wv[cur][ks * 12 + c];
        acc[0][c] = __builtin_amdgcn_mfma_f32_16x16x32_bf16(a0, bw, acc[0][c], 0, 0, 0);
        acc[1][c] = __builtin_amdgcn_mfma_f32_16x16x32_bf16(a1, bw, acc[1][c], 0, 0, 0);
      }
    }
    __builtin_amdgcn_sched_barrier(0);  // keep next stage's loads out too
  }

  // epilogue: C/D col=l15, row=q4*4+rr (per rowtile rt)
  const int b = r0 >> 10, s0 = r0 & 1023;
#pragma unroll
  for (int c = 0; c < 12; ++c) {
    const int mtx = c >> 2;
    const int h = (c & 3) * 16 + l15;
    if (mtx < 2) {
      const float bias = (mtx == 0 ? bq : bk)[h];
      short* op = (mtx == 0) ? Qg : Kg;
#pragma unroll
      for (int rt = 0; rt < 2; ++rt)
#pragma unroll
        for (int rr = 0; rr < 4; ++rr) {
          int row = wr0 + rt * 16 + q4 * 4 + rr;
          float v = acc[rt][c][rr] + bias;
          if (mtx == 0) v *= QSCALE;
          op[(size_t)row * 64 + h] = f2b(v);
        }
    } else {
      const float bias = bv[h];
#pragma unroll
      for (int rt = 0; rt < 2; ++rt) {
        uint2 sv;
        sv.x = pk2(acc[rt][c][0] + bias, acc[rt][c][1] + bias);
        sv.y = pk2(acc[rt][c][2] + bias, acc[rt][c][3] + bias);
        *(uint2*)(Vt + ((size_t)(b * 64 + h) << 10) +
                  (s0 + wid * 32 + rt * 16 + q4 * 4)) = sv;
      }
    }
  }
}

// ---------------- kernel 2: flash attention, BN=128, swapped QK^T ----------
// grid (32 batches fast, 16 levels); level 0 -> t=0, level L -> t=16-L (LPT).
__global__ __launch_bounds__(256, 2) void attn_kernel(
    const short* __restrict__ Qg, const short* __restrict__ Kg,
    const short* __restrict__ Vt, const float* __restrict__ padneg,
    float* __restrict__ out) {
  __shared__ short lK[2][2][128][32];  // [buf][dhalf][key][d32]  32 KB
  __shared__ short lV[2][4][64][32];   // [buf][kq][d][key32]     32 KB
  __shared__ short lOnes[16][32];      // ones B-tile (row0=1.0)  1 KB

  const int b = blockIdx.x;
  const int level = blockIdx.y;
  const int t = (level == 0) ? 0 : 16 - level;
  const int tid = threadIdx.x;
  const int wid = tid >> 6, lane = tid & 63;
  const int l15 = lane & 15, q4 = lane >> 4;
  const int qs = t * 64;
  const size_t base = (size_t)b * 1024;
  const int nkt = (t == 0) ? 8 : (t / 2 + 1);

  {  // init ones tile: 512 shorts
    int i0 = tid, i1 = tid + 256;
    ((short*)lOnes)[i0] = ((i0 >> 5) == 0) ? (short)0x3F80 : (short)0;
    if (i1 < 512) ((short*)lOnes)[i1] = ((i1 >> 5) == 0) ? (short)0x3F80 : (short)0;
  }

  // Q B-frags straight from global (lane row = query = qs + wid*16 + l15)
  const short* qrow = Qg + (base + qs + wid * 16 + l15) * 64;
  bf16x8 bq0 = *(const bf16x8*)(qrow + q4 * 8);
  bf16x8 bq1 = *(const bf16x8*)(qrow + 32 + q4 * 8);
  const int qi = qs + wid * 16 + l15;  // this lane's query row

  const int sr = lane >> 2, sc = (lane & 3) * 8;
  auto wlds_tile = [&](int buf, int kt) {
    const int kb = kt * 128;
    // K: 128 keys x 64 d; wave wid covers key quarter wid*32
#pragma unroll
    for (int i = 0; i < 4; ++i) {
      const int dh = i & 1, krow = wid * 32 + (i >> 1) * 16;
      GLDS16(Kg + (base + kb + krow + sr) * 64 + dh * 32 + sc,
             &lK[buf][dh][krow][0]);
    }
    // V: 64 d x 128 keys from Vt[b][d][s]; wave wid covers d strip wid*16
#pragma unroll
    for (int kq = 0; kq < 4; ++kq) {
      GLDS16(Vt + ((size_t)(b * 64 + wid * 16 + sr) << 10) + kb + kq * 32 + sc,
             &lV[buf][kq][wid * 16][0]);
    }
  };

  // padneg for this lane's keys: key = kb + c*16 + q4*4 + rr  -> float4
  float4 pnv[8];
  auto pnload = [&](int kt) {
#pragma unroll
    for (int c = 0; c < 8; ++c)
      pnv[c] = *(const float4*)(padneg + base + kt * 128 + c * 16 + q4 * 4);
  };

  pnload(0);
  wlds_tile(0, 0);
  __syncthreads();

  f32x4 o[5];  // o[4] = row-sum l via ones tile
#pragma unroll
  for (int c = 0; c < 5; ++c) o[c] = (f32x4){0.f, 0.f, 0.f, 0.f};

  for (int kt = 0; kt < nkt; ++kt) {
    const int cur = kt & 1;
    const int kb = kt * 128;

    // S^T = K Q^T: accumulator pre-loaded with padneg (pad mask is free)
    f32x4 s4[8];
#pragma unroll
    for (int c = 0; c < 8; ++c)
      s4[c] = (f32x4){pnv[c].x, pnv[c].y, pnv[c].z, pnv[c].w};

    if (kt + 1 < nkt) {
      wlds_tile(cur ^ 1, kt + 1);  // in flight until body-end barrier
      pnload(kt + 1);              // pnv already consumed into s4
    }

    // swapped QK^T: D row (q4*4+rr) = key, col (l15) = query
#pragma unroll
    for (int c = 0; c < 8; ++c) {
      bf16x8 a0 = *(const bf16x8*)&lK[cur][0][c * 16 + l15][q4 * 8];
      s4[c] = __builtin_amdgcn_mfma_f32_16x16x32_bf16(a0, bq0, s4[c], 0, 0, 0);
      bf16x8 a1 = *(const bf16x8*)&lK[cur][1][c * 16 + l15][q4 * 8];
      s4[c] = __builtin_amdgcn_mfma_f32_16x16x32_bf16(a1, bq1, s4[c], 0, 0, 0);
    }

    // fixed-max softmax in place: p = exp2(min(s,80)); causal/img masks
    const bool diag = (t == 0) ? (kt == 0) : (kt == nkt - 1);
    const bool img = (t == 0 && kt > 0);
#pragma unroll
    for (int c = 0; c < 8; ++c) {
#pragma unroll
      for (int rr = 0; rr < 4; ++rr) {
        float pv = exp2f(fminf(s4[c][rr], 80.f));
        if (diag) {
          int j = kb + c * 16 + q4 * 4 + rr;
          if (qi >= NIP && j > qi) pv = 0.f;
        }
        if (img) {
          if (qi >= NIP) pv = 0.f;
        }
        s4[c][rr] = pv;
      }
    }

    // PV: per 32-key block, assemble bf16 A-frag fully in registers.
    // w0..w3 = cvt_pk key-pairs; (X0,X2)=permlane16(permlane32(w0,w2)),
    // (X1,X3)= same on (w1,w3).  A-frag keys = q4*8 + 0..7.
#pragma unroll
    for (int m = 0; m < 4; ++m) {
      uint32_t w0 = pk2(s4[2 * m][0], s4[2 * m][1]);
      uint32_t w1 = pk2(s4[2 * m][2], s4[2 * m][3]);
      uint32_t w2 = pk2(s4[2 * m + 1][0], s4[2 * m + 1][1]);
      uint32_t w3 = pk2(s4[2 * m + 1][2], s4[2 * m + 1][3]);
      asm("v_permlane32_swap_b32 %0, %1" : "+v"(w0), "+v"(w2));
      asm("v_permlane32_swap_b32 %0, %1" : "+v"(w1), "+v"(w3));
      asm("v_permlane16_swap_b32 %0, %1" : "+v"(w0), "+v"(w2));
      asm("v_permlane16_swap_b32 %0, %1" : "+v"(w1), "+v"(w3));
      union { uint32_t u[4]; bf16x8 v; } af;
      af.u[0] = w0; af.u[1] = w1; af.u[2] = w2; af.u[3] = w3;
#pragma unroll
      for (int c = 0; c < 5; ++c) {
        bf16x8 bv = (c < 4) ? *(const bf16x8*)&lV[cur][m][c * 16 + l15][q4 * 8]
                            : *(const bf16x8*)&lOnes[l15][q4 * 8];
        o[c] = __builtin_amdgcn_mfma_f32_16x16x32_bf16(af.v, bv, o[c], 0, 0, 0);
      }
    }
    __syncthreads();
  }

#pragma unroll
  for (int rr = 0; rr < 4; ++rr) {
    float l = __shfl(o[4][rr], lane & 48, 64);  // col 0 of this quad
    const float inv = (l > 0.f) ? 1.0f / l : 0.f;
    const size_t row = base + qs + wid * 16 + q4 * 4 + rr;
#pragma unroll
    for (int c = 0; c < 4; ++c)
      out[row * 64 + c * 16 + l15] = o[c][rr] * inv;
  }
}

extern "C" void kernel_launch(void* const* d_in, const int* in_sizes, int n_in,
                              void* d_out, int out_size, void* d_ws, size_t ws_size,
                              hipStream_t stream) {
  const float* X  = (const float*)d_in[0];
  const float* Wq = (const float*)d_in[1];
  const float* bq = (const float*)d_in[2];
  const float* Wk = (const float*)d_in[3];
  const float* bk = (const float*)d_in[4];
  const float* Wv = (const float*)d_in[5];
  const float* bv = (const float*)d_in[6];
  const int* pad  = (const int*)d_in[8];
  float* out = (float*)d_out;

  short* Qg = (short*)d_ws;              // 4 MB
  short* Kg = Qg + 32768 * 64;           // 4 MB
  short* Vt = Kg + 32768 * 64;           // 4 MB, [32][64][1024]
  short* Wt = Vt + 32768 * 64;           // 288 KB, row-major [192][768]
  float* padneg = (float*)(Wt + 147456); // 128 KB

  wt_kernel<<<576, 256, 0, stream>>>(Wq, Wk, Wv, pad, Wt, padneg);
  proj_kernel<<<256, 256, 0, stream>>>(X, bq, bk, bv, Wt, Qg, Kg, Vt);
  attn_kernel<<<dim3(32, 16), 256, 0, stream>>>(Qg, Kg, Vt, padneg, out);
}